// Round 3
// baseline (67.878 us; speedup 1.0000x reference)
//
#include <hip/hip_runtime.h>
#include <stdint.h>

#define NB 4
#define NT 2048
#define NC 1024
#define NH 64
#define NM (NB*NT)

typedef unsigned short u16;
typedef __bf16 bf16_t;
typedef float f32x4 __attribute__((ext_vector_type(4)));
typedef bf16_t bf16x8 __attribute__((ext_vector_type(8)));
typedef u16 u16x8 __attribute__((ext_vector_type(8)));
typedef u16 u16x4 __attribute__((ext_vector_type(4)));

__device__ __forceinline__ u16 f2b(float f) {
  return __builtin_bit_cast(u16, (bf16_t)f);
}

// ---------------- Wq/Wk/Wv [1024][64] f32 -> WT [3][64][1024] bf16 (transposed)
__global__ __launch_bounds__(256) void wt_kernel(const float* __restrict__ Wq,
                                                 const float* __restrict__ Wk,
                                                 const float* __restrict__ Wv,
                                                 u16* __restrict__ wt) {
  __shared__ float t[64][65];
  const int m = blockIdx.x >> 4;
  const int kt = blockIdx.x & 15;
  const int k0 = kt * 64;
  const float* W = (m == 0) ? Wq : (m == 1) ? Wk : Wv;
  {
    const int r = threadIdx.x >> 2, c4 = threadIdx.x & 3;
    #pragma unroll
    for (int j = 0; j < 4; ++j) {
      const float4 f = *(const float4*)(W + (size_t)(k0 + r) * NH + c4 * 16 + j * 4);
      t[r][c4 * 16 + j * 4 + 0] = f.x;
      t[r][c4 * 16 + j * 4 + 1] = f.y;
      t[r][c4 * 16 + j * 4 + 2] = f.z;
      t[r][c4 * 16 + j * 4 + 3] = f.w;
    }
  }
  __syncthreads();
  const int n = threadIdx.x >> 2, kc = threadIdx.x & 3;
  u16x8 a, b;
  #pragma unroll
  for (int j = 0; j < 8; ++j) a[j] = f2b(t[kc * 16 + j][n]);
  #pragma unroll
  for (int j = 0; j < 8; ++j) b[j] = f2b(t[kc * 16 + 8 + j][n]);
  u16* dst = wt + ((size_t)(m * 64 + n)) * NC + k0 + kc * 16;
  *(u16x8*)dst = a;
  *(u16x8*)(dst + 8) = b;
}

// ---------------- fused QKV projection, 2-way K-split
// 8 waves = 2 ksplits x (2 row-subtiles x 2 N-halves); split-1 partials merged via LDS
__global__ __launch_bounds__(512) void proj_kernel(const float* __restrict__ x,
                                                   const u16* __restrict__ wt,
                                                   u16* __restrict__ qo,
                                                   u16* __restrict__ ko,
                                                   u16* __restrict__ vto) {
  __shared__ u16 sA[2][32 * 64];    // per-split [row][k] bf16, 16B-chunk XOR swizzle
  __shared__ u16 sB[2][192 * 64];   // per-split [n][k] bf16
  __shared__ float po[4][6][16][17];// split-1 partials [wv2][fn6][row][li]
  const int tid = threadIdx.x;
  const int lane = tid & 63;
  const int wv = tid >> 6;          // 0..7
  const int s = wv >> 2;            // k-split
  const int wv2 = wv & 3;
  const int w = wv2 & 1;            // row subtile
  const int h = wv2 >> 1;           // n half
  const int g = lane >> 4;
  const int li = lane & 15;
  const int row0 = blockIdx.x * 32;
  const int gtid = tid & 255;       // id within split

  const f32x4 zero = {0.f, 0.f, 0.f, 0.f};
  f32x4 acc[6];
  #pragma unroll
  for (int i = 0; i < 6; ++i) acc[i] = zero;

  const int r = gtid >> 3;          // 0..31 staging row
  const int fc = gtid & 7;          // 8-float chunk
  const float* xsrc = x + (size_t)(row0 + r) * NC + fc * 8;

  for (int kt8 = 0; kt8 < 8; ++kt8) {
    const int k0 = (s * 8 + kt8) * 64;
    // stage A: 32x64 fp32 -> bf16
    {
      const float4 f0 = *(const float4*)(xsrc + k0);
      const float4 f1 = *(const float4*)(xsrc + k0 + 4);
      u16x8 u0;
      u0[0]=f2b(f0.x); u0[1]=f2b(f0.y); u0[2]=f2b(f0.z); u0[3]=f2b(f0.w);
      u0[4]=f2b(f1.x); u0[5]=f2b(f1.y); u0[6]=f2b(f1.z); u0[7]=f2b(f1.w);
      *(u16x8*)&sA[s][r * 64 + ((fc ^ (r & 7)) * 8)] = u0;
    }
    // stage B: 192x64 bf16 from WT (L2-resident)
    #pragma unroll
    for (int it = 0; it < 6; ++it) {
      const int cid = it * 256 + gtid;
      const int n = cid >> 3;
      const int c = cid & 7;
      const u16x8 v = *(const u16x8*)(wt + (size_t)n * NC + k0 + c * 8);
      *(u16x8*)&sB[s][n * 64 + ((c ^ (n & 7)) * 8)] = v;
    }
    __syncthreads();
    #pragma unroll
    for (int ks = 0; ks < 2; ++ks) {
      const int ar = w * 16 + li;
      const bf16x8 a = *(const bf16x8*)&sA[s][ar * 64 + (((ks * 4 + g) ^ (ar & 7)) * 8)];
      #pragma unroll
      for (int fn6 = 0; fn6 < 6; ++fn6) {
        const int n = (h * 6 + fn6) * 16 + li;
        const bf16x8 b = *(const bf16x8*)&sB[s][n * 64 + (((ks * 4 + g) ^ (n & 7)) * 8)];
        acc[fn6] = __builtin_amdgcn_mfma_f32_16x16x32_bf16(a, b, acc[fn6], 0, 0, 0);
      }
    }
    __syncthreads();
  }

  if (s == 1) {
    #pragma unroll
    for (int fn6 = 0; fn6 < 6; ++fn6)
      #pragma unroll
      for (int i = 0; i < 4; ++i)
        po[wv2][fn6][g * 4 + i][li] = acc[fn6][i];
  }
  __syncthreads();
  if (s == 0) {
    #pragma unroll
    for (int fn6 = 0; fn6 < 6; ++fn6)
      #pragma unroll
      for (int i = 0; i < 4; ++i)
        acc[fn6][i] += po[wv2][fn6][g * 4 + i][li];

    // epilogue: C/D layout col=lane&15, row=(lane>>4)*4+reg
    const int rr0 = row0 + w * 16 + g * 4;
    #pragma unroll
    for (int fn6 = 0; fn6 < 6; ++fn6) {
      const int fn = h * 6 + fn6;
      if (fn < 4) {
        #pragma unroll
        for (int i = 0; i < 4; ++i)
          qo[(size_t)(rr0 + i) * NH + fn * 16 + li] = f2b(acc[fn6][i]);
      } else if (fn < 8) {
        #pragma unroll
        for (int i = 0; i < 4; ++i)
          ko[(size_t)(rr0 + i) * NH + (fn - 4) * 16 + li] = f2b(acc[fn6][i]);
      } else {
        u16x4 pv;
        #pragma unroll
        for (int i = 0; i < 4; ++i) pv[i] = f2b(acc[fn6][i]);
        const int hs = (fn - 8) * 16 + li;
        const int bidx = rr0 >> 11;
        const int tt = rr0 & 2047;
        *(u16x4*)&vto[((size_t)(bidx * 64 + hs)) * NT + tt] = pv;
      }
    }
  }
}

// ---------------- flash-style causal attention, barrier-free main loop
// grid (64,4): one 32-row q-tile per block; 8 waves = 4 kv-splits x 2 q-subwaves.
// K and V^T fragments are read DIRECTLY from global (L2-resident) — no staging,
// no __syncthreads in the loop; each wave runs its kv-split independently.
__global__ __launch_bounds__(512) void attn_kernel(const u16* __restrict__ qg,
                                                   const u16* __restrict__ kg,
                                                   const u16* __restrict__ vtg,
                                                   float* __restrict__ out) {
  __shared__ u16 sP[8][16 * 64];     // per-wave P tile [q][kv] swizzled
  __shared__ float po[4][2][16][68]; // merge: per-split partial O
  __shared__ float pml[4][2][16][2]; // merge: per-split (m, l)
  const int tid = threadIdx.x;
  const int lane = tid & 63;
  const int wv = tid >> 6;           // 0..7
  const int s = wv >> 1;             // kv split 0..3
  const int w = wv & 1;              // q subtile
  const int g = lane >> 4;
  const int li = lane & 15;
  const int jt = blockIdx.x;
  const int bb = blockIdx.y;
  const size_t bt0 = (size_t)bb * NT;
  const int q0w = jt * 32 + w * 16;

  bf16x8 aq[2];
  #pragma unroll
  for (int ks = 0; ks < 2; ++ks)
    aq[ks] = *(const bf16x8*)(qg + (bt0 + q0w + li) * NH + ks * 32 + g * 8);

  const f32x4 zero = {0.f, 0.f, 0.f, 0.f};
  f32x4 o[4];
  float mrow[4], lrow[4];
  #pragma unroll
  for (int i = 0; i < 4; ++i) { o[i] = zero; mrow[i] = -1e30f; lrow[i] = 0.f; }

  const int nkv = jt / 2 + 1;

  for (int t = s; t < nkv; t += 4) {
    const int kv0 = t * 64;
    // S = Q K^T  — B-fragments straight from global
    f32x4 sc[4];
    #pragma unroll
    for (int fn = 0; fn < 4; ++fn) sc[fn] = zero;
    #pragma unroll
    for (int ks = 0; ks < 2; ++ks) {
      #pragma unroll
      for (int fn = 0; fn < 4; ++fn) {
        const bf16x8 bk = *(const bf16x8*)(kg + (bt0 + kv0 + fn * 16 + li) * NH + ks * 32 + g * 8);
        sc[fn] = __builtin_amdgcn_mfma_f32_16x16x32_bf16(aq[ks], bk, sc[fn], 0, 0, 0);
      }
    }

    // scale + causal mask + online softmax (row = 16-lane group)
    float p[4][4];
    const bool needmask = (kv0 + 63 > q0w);
    #pragma unroll
    for (int fn = 0; fn < 4; ++fn) {
      #pragma unroll
      for (int i = 0; i < 4; ++i) {
        float v = sc[fn][i] * 0.125f;
        if (needmask && (kv0 + fn * 16 + li > q0w + g * 4 + i)) v = -1e30f;
        p[fn][i] = v;
      }
    }
    #pragma unroll
    for (int i = 0; i < 4; ++i) {
      float tm = fmaxf(fmaxf(p[0][i], p[1][i]), fmaxf(p[2][i], p[3][i]));
      tm = fmaxf(tm, __shfl_xor(tm, 1));
      tm = fmaxf(tm, __shfl_xor(tm, 2));
      tm = fmaxf(tm, __shfl_xor(tm, 4));
      tm = fmaxf(tm, __shfl_xor(tm, 8));
      const float newm = fmaxf(mrow[i], tm);
      const float scold = __expf(mrow[i] - newm);
      mrow[i] = newm;
      float rs = 0.f;
      #pragma unroll
      for (int fn = 0; fn < 4; ++fn) {
        const float e = __expf(p[fn][i] - newm);
        p[fn][i] = e;
        rs += e;
      }
      rs += __shfl_xor(rs, 1);
      rs += __shfl_xor(rs, 2);
      rs += __shfl_xor(rs, 4);
      rs += __shfl_xor(rs, 8);
      lrow[i] = lrow[i] * scold + rs;
      #pragma unroll
      for (int fn = 0; fn < 4; ++fn) o[fn][i] *= scold;
    }

    // P (bf16) -> per-wave LDS tile in A-fragment layout (wave-local, no barrier)
    #pragma unroll
    for (int fn = 0; fn < 4; ++fn) {
      #pragma unroll
      for (int i = 0; i < 4; ++i) {
        const int ql = g * 4 + i;
        const int kv = fn * 16 + li;
        sP[wv][ql * 64 + (((kv >> 3) ^ (ql & 7)) * 8) + (kv & 7)] = f2b(p[fn][i]);
      }
    }
    // O += P V — V-fragments straight from global
    #pragma unroll
    for (int ks = 0; ks < 2; ++ks) {
      const bf16x8 pa = *(const bf16x8*)&sP[wv][li * 64 + (((ks * 4 + g) ^ (li & 7)) * 8)];
      #pragma unroll
      for (int fn = 0; fn < 4; ++fn) {
        const bf16x8 bv = *(const bf16x8*)(vtg + ((size_t)(bb * 64 + fn * 16 + li)) * NT + kv0 + ks * 32 + g * 8);
        o[fn] = __builtin_amdgcn_mfma_f32_16x16x32_bf16(pa, bv, o[fn], 0, 0, 0);
      }
    }
  }

  // ---- merge 4 kv-splits
  #pragma unroll
  for (int fn = 0; fn < 4; ++fn)
    #pragma unroll
    for (int i = 0; i < 4; ++i)
      po[s][w][g * 4 + i][fn * 16 + li] = o[fn][i];
  if (li == 0) {
    #pragma unroll
    for (int i = 0; i < 4; ++i) {
      pml[s][w][g * 4 + i][0] = mrow[i];
      pml[s][w][g * 4 + i][1] = lrow[i];
    }
  }
  __syncthreads();
  if (s == 0) {
    float es[4][4], Li[4];
    #pragma unroll
    for (int i = 0; i < 4; ++i) {
      const int row = g * 4 + i;
      float M = pml[0][w][row][0];
      #pragma unroll
      for (int s4 = 1; s4 < 4; ++s4) M = fmaxf(M, pml[s4][w][row][0]);
      float L = 0.f;
      #pragma unroll
      for (int s4 = 0; s4 < 4; ++s4) {
        const float e = __expf(pml[s4][w][row][0] - M);
        es[i][s4] = e;
        L += pml[s4][w][row][1] * e;
      }
      Li[i] = L;
    }
    #pragma unroll
    for (int fn = 0; fn < 4; ++fn) {
      #pragma unroll
      for (int i = 0; i < 4; ++i) {
        float acc = 0.f;
        #pragma unroll
        for (int s4 = 0; s4 < 4; ++s4)
          acc += po[s4][w][g * 4 + i][fn * 16 + li] * es[i][s4];
        out[(bt0 + q0w + g * 4 + i) * NH + fn * 16 + li] = acc / Li[i];
      }
    }
  }
}

extern "C" void kernel_launch(void* const* d_in, const int* in_sizes, int n_in,
                              void* d_out, int out_size, void* d_ws, size_t ws_size,
                              hipStream_t stream) {
  (void)in_sizes; (void)n_in; (void)out_size; (void)ws_size;
  const float* x  = (const float*)d_in[0];
  const float* Wq = (const float*)d_in[1];
  const float* Wk = (const float*)d_in[2];
  const float* Wv = (const float*)d_in[3];
  float* out = (float*)d_out;
  char* ws = (char*)d_ws;
  u16* qb  = (u16*)(ws);                    // 1 MB  : q bf16 [8192][64]
  u16* kb  = (u16*)(ws + (1u << 20));       // 1 MB  : k bf16 [8192][64]
  u16* vtb = (u16*)(ws + (2u << 20));       // 1 MB  : v^T bf16 [4][64][2048]
  u16* wtb = (u16*)(ws + (3u << 20));       // 384 KB: WT bf16 [3][64][1024]
  hipLaunchKernelGGL(wt_kernel,   dim3(48),    dim3(256), 0, stream, Wq, Wk, Wv, wtb);
  hipLaunchKernelGGL(proj_kernel, dim3(256),   dim3(512), 0, stream, x, wtb, qb, kb, vtb);
  hipLaunchKernelGGL(attn_kernel, dim3(64, 4), dim3(512), 0, stream, qb, kb, vtb, out);
}

// Round 4
// 60.088 us; speedup vs baseline: 1.1296x; 1.1296x over previous
//
#include <hip/hip_runtime.h>
#include <stdint.h>

#define NB 4
#define NT 2048
#define NC 1024
#define NH 64
#define NM (NB*NT)

typedef unsigned short u16;
typedef __bf16 bf16_t;
typedef float f32x4 __attribute__((ext_vector_type(4)));
typedef bf16_t bf16x8 __attribute__((ext_vector_type(8)));
typedef u16 u16x8 __attribute__((ext_vector_type(8)));
typedef u16 u16x4 __attribute__((ext_vector_type(4)));

__device__ __forceinline__ u16 f2b(float f) {
  return __builtin_bit_cast(u16, (bf16_t)f);
}
__device__ __forceinline__ float b2f(u16 u) {
  return (float)__builtin_bit_cast(bf16_t, u);
}

// ---------------- Wq/Wk/Wv [1024][64] f32 -> WT [3][64][1024] bf16 (transposed)
__global__ __launch_bounds__(256) void wt_kernel(const float* __restrict__ Wq,
                                                 const float* __restrict__ Wk,
                                                 const float* __restrict__ Wv,
                                                 u16* __restrict__ wt) {
  __shared__ float t[64][65];
  const int m = blockIdx.x >> 4;
  const int kt = blockIdx.x & 15;
  const int k0 = kt * 64;
  const float* W = (m == 0) ? Wq : (m == 1) ? Wk : Wv;
  {
    const int r = threadIdx.x >> 2, c4 = threadIdx.x & 3;
    #pragma unroll
    for (int j = 0; j < 4; ++j) {
      const float4 f = *(const float4*)(W + (size_t)(k0 + r) * NH + c4 * 16 + j * 4);
      t[r][c4 * 16 + j * 4 + 0] = f.x;
      t[r][c4 * 16 + j * 4 + 1] = f.y;
      t[r][c4 * 16 + j * 4 + 2] = f.z;
      t[r][c4 * 16 + j * 4 + 3] = f.w;
    }
  }
  __syncthreads();
  const int n = threadIdx.x >> 2, kc = threadIdx.x & 3;
  u16x8 a, b;
  #pragma unroll
  for (int j = 0; j < 8; ++j) a[j] = f2b(t[kc * 16 + j][n]);
  #pragma unroll
  for (int j = 0; j < 8; ++j) b[j] = f2b(t[kc * 16 + 8 + j][n]);
  u16* dst = wt + ((size_t)(m * 64 + n)) * NC + k0 + kc * 16;
  *(u16x8*)dst = a;
  *(u16x8*)(dst + 8) = b;
}

// ---------------- fused QKV projection, 2-way K-split (unchanged from r3)
__global__ __launch_bounds__(512) void proj_kernel(const float* __restrict__ x,
                                                   const u16* __restrict__ wt,
                                                   u16* __restrict__ qo,
                                                   u16* __restrict__ ko,
                                                   u16* __restrict__ vto) {
  __shared__ u16 sA[2][32 * 64];
  __shared__ u16 sB[2][192 * 64];
  __shared__ float po[4][6][16][17];
  const int tid = threadIdx.x;
  const int lane = tid & 63;
  const int wv = tid >> 6;
  const int s = wv >> 2;
  const int wv2 = wv & 3;
  const int w = wv2 & 1;
  const int h = wv2 >> 1;
  const int g = lane >> 4;
  const int li = lane & 15;
  const int row0 = blockIdx.x * 32;
  const int gtid = tid & 255;

  const f32x4 zero = {0.f, 0.f, 0.f, 0.f};
  f32x4 acc[6];
  #pragma unroll
  for (int i = 0; i < 6; ++i) acc[i] = zero;

  const int r = gtid >> 3;
  const int fc = gtid & 7;
  const float* xsrc = x + (size_t)(row0 + r) * NC + fc * 8;

  for (int kt8 = 0; kt8 < 8; ++kt8) {
    const int k0 = (s * 8 + kt8) * 64;
    {
      const float4 f0 = *(const float4*)(xsrc + k0);
      const float4 f1 = *(const float4*)(xsrc + k0 + 4);
      u16x8 u0;
      u0[0]=f2b(f0.x); u0[1]=f2b(f0.y); u0[2]=f2b(f0.z); u0[3]=f2b(f0.w);
      u0[4]=f2b(f1.x); u0[5]=f2b(f1.y); u0[6]=f2b(f1.z); u0[7]=f2b(f1.w);
      *(u16x8*)&sA[s][r * 64 + ((fc ^ (r & 7)) * 8)] = u0;
    }
    #pragma unroll
    for (int it = 0; it < 6; ++it) {
      const int cid = it * 256 + gtid;
      const int n = cid >> 3;
      const int c = cid & 7;
      const u16x8 v = *(const u16x8*)(wt + (size_t)n * NC + k0 + c * 8);
      *(u16x8*)&sB[s][n * 64 + ((c ^ (n & 7)) * 8)] = v;
    }
    __syncthreads();
    #pragma unroll
    for (int ks = 0; ks < 2; ++ks) {
      const int ar = w * 16 + li;
      const bf16x8 a = *(const bf16x8*)&sA[s][ar * 64 + (((ks * 4 + g) ^ (ar & 7)) * 8)];
      #pragma unroll
      for (int fn6 = 0; fn6 < 6; ++fn6) {
        const int n = (h * 6 + fn6) * 16 + li;
        const bf16x8 b = *(const bf16x8*)&sB[s][n * 64 + (((ks * 4 + g) ^ (n & 7)) * 8)];
        acc[fn6] = __builtin_amdgcn_mfma_f32_16x16x32_bf16(a, b, acc[fn6], 0, 0, 0);
      }
    }
    __syncthreads();
  }

  if (s == 1) {
    #pragma unroll
    for (int fn6 = 0; fn6 < 6; ++fn6)
      #pragma unroll
      for (int i = 0; i < 4; ++i)
        po[wv2][fn6][g * 4 + i][li] = acc[fn6][i];
  }
  __syncthreads();
  if (s == 0) {
    #pragma unroll
    for (int fn6 = 0; fn6 < 6; ++fn6)
      #pragma unroll
      for (int i = 0; i < 4; ++i)
        acc[fn6][i] += po[wv2][fn6][g * 4 + i][li];

    const int rr0 = row0 + w * 16 + g * 4;
    #pragma unroll
    for (int fn6 = 0; fn6 < 6; ++fn6) {
      const int fn = h * 6 + fn6;
      if (fn < 4) {
        #pragma unroll
        for (int i = 0; i < 4; ++i)
          qo[(size_t)(rr0 + i) * NH + fn * 16 + li] = f2b(acc[fn6][i]);
      } else if (fn < 8) {
        #pragma unroll
        for (int i = 0; i < 4; ++i)
          ko[(size_t)(rr0 + i) * NH + (fn - 4) * 16 + li] = f2b(acc[fn6][i]);
      } else {
        u16x4 pv;
        #pragma unroll
        for (int i = 0; i < 4; ++i) pv[i] = f2b(acc[fn6][i]);
        const int hs = (fn - 8) * 16 + li;
        const int bidx = rr0 >> 11;
        const int tt = rr0 & 2047;
        *(u16x4*)&vto[((size_t)(bidx * 64 + hs)) * NT + tt] = pv;
      }
    }
  }
}

// ---------------- attention phase A: split-KV across blocks (8-way), no barriers
// grid (64 jt, 4 bb, 4 z) x 256 thr; wave = (qsub, ss); split S8 = z*2+ss.
// Each wave: tiles t = S8, S8+8, ... ; writes unnormalized partial (o bf16, m/l f32).
__global__ __launch_bounds__(256, 4) void attn_kernel(const u16* __restrict__ qg,
                                                      const u16* __restrict__ kg,
                                                      const u16* __restrict__ vtg,
                                                      u16* __restrict__ pO,
                                                      float* __restrict__ pML) {
  __shared__ u16 sP[4][16 * 64];     // per-wave P tile [q][kv] swizzled
  const int tid = threadIdx.x;
  const int lane = tid & 63;
  const int wv = tid >> 6;           // 0..3
  const int qsub = wv & 1;
  const int ss = wv >> 1;
  const int g = lane >> 4;
  const int li = lane & 15;
  const int jt = blockIdx.x;
  const int bb = blockIdx.y;
  const int S8 = blockIdx.z * 2 + ss;
  const size_t bt0 = (size_t)bb * NT;
  const int q0w = jt * 32 + qsub * 16;

  bf16x8 aq[2];
  #pragma unroll
  for (int ks = 0; ks < 2; ++ks)
    aq[ks] = *(const bf16x8*)(qg + (bt0 + q0w + li) * NH + ks * 32 + g * 8);

  const f32x4 zero = {0.f, 0.f, 0.f, 0.f};
  f32x4 o[4];
  float mrow[4], lrow[4];
  #pragma unroll
  for (int i = 0; i < 4; ++i) { o[i] = zero; mrow[i] = -1e30f; lrow[i] = 0.f; }

  const int nkv = jt / 2 + 1;

  for (int t = S8; t < nkv; t += 8) {
    const int kv0 = t * 64;
    // --- K fragments into regs (8 independent loads, batched)
    bf16x8 kf[2][4];
    #pragma unroll
    for (int ks = 0; ks < 2; ++ks)
      #pragma unroll
      for (int fn = 0; fn < 4; ++fn)
        kf[ks][fn] = *(const bf16x8*)(kg + (bt0 + kv0 + fn * 16 + li) * NH + ks * 32 + g * 8);
    // --- S = Q K^T
    f32x4 sc[4];
    #pragma unroll
    for (int fn = 0; fn < 4; ++fn) sc[fn] = zero;
    #pragma unroll
    for (int ks = 0; ks < 2; ++ks)
      #pragma unroll
      for (int fn = 0; fn < 4; ++fn)
        sc[fn] = __builtin_amdgcn_mfma_f32_16x16x32_bf16(aq[ks], kf[ks][fn], sc[fn], 0, 0, 0);

    // --- V fragments: issue early, consumed after softmax
    bf16x8 vf[2][4];
    #pragma unroll
    for (int ks = 0; ks < 2; ++ks)
      #pragma unroll
      for (int fn = 0; fn < 4; ++fn)
        vf[ks][fn] = *(const bf16x8*)(vtg + ((size_t)(bb * 64 + fn * 16 + li)) * NT + kv0 + ks * 32 + g * 8);

    // --- scale + causal mask + online softmax (row = 16-lane group)
    float p[4][4];
    const bool needmask = (kv0 + 63 > q0w);
    #pragma unroll
    for (int fn = 0; fn < 4; ++fn) {
      #pragma unroll
      for (int i = 0; i < 4; ++i) {
        float v = sc[fn][i] * 0.125f;
        if (needmask && (kv0 + fn * 16 + li > q0w + g * 4 + i)) v = -1e30f;
        p[fn][i] = v;
      }
    }
    #pragma unroll
    for (int i = 0; i < 4; ++i) {
      float tm = fmaxf(fmaxf(p[0][i], p[1][i]), fmaxf(p[2][i], p[3][i]));
      tm = fmaxf(tm, __shfl_xor(tm, 1));
      tm = fmaxf(tm, __shfl_xor(tm, 2));
      tm = fmaxf(tm, __shfl_xor(tm, 4));
      tm = fmaxf(tm, __shfl_xor(tm, 8));
      const float newm = fmaxf(mrow[i], tm);
      const float scold = __expf(mrow[i] - newm);
      mrow[i] = newm;
      float rs = 0.f;
      #pragma unroll
      for (int fn = 0; fn < 4; ++fn) {
        const float e = __expf(p[fn][i] - newm);
        p[fn][i] = e;
        rs += e;
      }
      rs += __shfl_xor(rs, 1);
      rs += __shfl_xor(rs, 2);
      rs += __shfl_xor(rs, 4);
      rs += __shfl_xor(rs, 8);
      lrow[i] = lrow[i] * scold + rs;
      #pragma unroll
      for (int fn = 0; fn < 4; ++fn) o[fn][i] *= scold;
    }

    // --- P -> per-wave LDS tile in A-fragment layout (wave-local, no barrier)
    #pragma unroll
    for (int fn = 0; fn < 4; ++fn) {
      #pragma unroll
      for (int i = 0; i < 4; ++i) {
        const int ql = g * 4 + i;
        const int kv = fn * 16 + li;
        sP[wv][ql * 64 + (((kv >> 3) ^ (ql & 7)) * 8) + (kv & 7)] = f2b(p[fn][i]);
      }
    }
    // --- O += P V
    #pragma unroll
    for (int ks = 0; ks < 2; ++ks) {
      const bf16x8 pa = *(const bf16x8*)&sP[wv][li * 64 + (((ks * 4 + g) ^ (li & 7)) * 8)];
      #pragma unroll
      for (int fn = 0; fn < 4; ++fn)
        o[fn] = __builtin_amdgcn_mfma_f32_16x16x32_bf16(pa, vf[ks][fn], o[fn], 0, 0, 0);
    }
  }

  // --- write partials: pO[S8][row][col] bf16, pML[S8][row][{m,l}] f32
  #pragma unroll
  for (int fn = 0; fn < 4; ++fn) {
    #pragma unroll
    for (int i = 0; i < 4; ++i) {
      const size_t row = bt0 + q0w + g * 4 + i;
      pO[((size_t)S8 * NM + row) * NH + fn * 16 + li] = f2b(o[fn][i]);
    }
  }
  if (li == 0) {
    #pragma unroll
    for (int i = 0; i < 4; ++i) {
      const size_t row = bt0 + q0w + g * 4 + i;
      pML[((size_t)S8 * NM + row) * 2 + 0] = mrow[i];
      pML[((size_t)S8 * NM + row) * 2 + 1] = lrow[i];
    }
  }
}

// ---------------- merge 8 KV-splits per row (LSE combine)
__global__ __launch_bounds__(256) void merge_kernel(const u16* __restrict__ pO,
                                                    const float* __restrict__ pML,
                                                    float* __restrict__ out) {
  const int gid = blockIdx.x * 256 + threadIdx.x;   // 0 .. NM*16-1
  const int row = gid >> 4;
  const int c0 = (gid & 15) * 4;
  float ms[8], ls[8];
  float M = -1e30f;
  #pragma unroll
  for (int s = 0; s < 8; ++s) {
    ms[s] = pML[((size_t)s * NM + row) * 2 + 0];
    ls[s] = pML[((size_t)s * NM + row) * 2 + 1];
    M = fmaxf(M, ms[s]);
  }
  float L = 0.f, es[8];
  #pragma unroll
  for (int s = 0; s < 8; ++s) {
    es[s] = __expf(ms[s] - M);
    L += ls[s] * es[s];
  }
  float acc0 = 0.f, acc1 = 0.f, acc2 = 0.f, acc3 = 0.f;
  #pragma unroll
  for (int s = 0; s < 8; ++s) {
    const u16x4 v = *(const u16x4*)&pO[((size_t)s * NM + row) * NH + c0];
    acc0 += b2f(v[0]) * es[s];
    acc1 += b2f(v[1]) * es[s];
    acc2 += b2f(v[2]) * es[s];
    acc3 += b2f(v[3]) * es[s];
  }
  const float inv = 1.f / L;
  float4 r = {acc0 * inv, acc1 * inv, acc2 * inv, acc3 * inv};
  *(float4*)&out[(size_t)row * NH + c0] = r;
}

extern "C" void kernel_launch(void* const* d_in, const int* in_sizes, int n_in,
                              void* d_out, int out_size, void* d_ws, size_t ws_size,
                              hipStream_t stream) {
  (void)in_sizes; (void)n_in; (void)out_size; (void)ws_size;
  const float* x  = (const float*)d_in[0];
  const float* Wq = (const float*)d_in[1];
  const float* Wk = (const float*)d_in[2];
  const float* Wv = (const float*)d_in[3];
  float* out = (float*)d_out;
  char* ws = (char*)d_ws;
  u16* qb   = (u16*)(ws);                    // 1 MB   : q bf16 [8192][64]
  u16* kb   = (u16*)(ws + (1u << 20));       // 1 MB   : k bf16 [8192][64]
  u16* vtb  = (u16*)(ws + (2u << 20));       // 1 MB   : v^T bf16 [4][64][2048]
  u16* wtb  = (u16*)(ws + (3u << 20));       // 384 KB : WT bf16 [3][64][1024]
  u16* pO   = (u16*)(ws + (4u << 20));       // 8 MB   : partial O bf16 [8][8192][64]
  float* pML = (float*)(ws + (12u << 20));   // 512 KB : partial m,l f32 [8][8192][2]
  hipLaunchKernelGGL(wt_kernel,    dim3(48),       dim3(256), 0, stream, Wq, Wk, Wv, wtb);
  hipLaunchKernelGGL(proj_kernel,  dim3(256),      dim3(512), 0, stream, x, wtb, qb, kb, vtb);
  hipLaunchKernelGGL(attn_kernel,  dim3(64, 4, 4), dim3(256), 0, stream, qb, kb, vtb, pO, pML);
  hipLaunchKernelGGL(merge_kernel, dim3(512),      dim3(256), 0, stream, pO, pML, out);
}